// Round 1
// baseline (2164.985 us; speedup 1.0000x reference)
//
#include <hip/hip_runtime.h>

#define NN 8192
#define DD 512
#define EE 262144

typedef __attribute__((ext_vector_type(4))) float f32x4;
typedef __attribute__((ext_vector_type(8))) short bf16x8;

__device__ inline unsigned short f2bf(float f) {
    unsigned u = __float_as_uint(f);
    u += 0x7fffu + ((u >> 16) & 1u);   // round-to-nearest-even
    return (unsigned short)(u >> 16);
}

// ---------------- row-sum normalize: out = in / (rowsum + 1e-4) ----------------
// one block per row, 256 threads, 2 floats/thread. Safe in-place (regs hold data).
__global__ void rownorm_kernel(const float* __restrict__ in, float* __restrict__ out) {
    __shared__ float red[256];
    int r = blockIdx.x, t = threadIdx.x;
    float2 v = ((const float2*)(in + (size_t)r * DD))[t];
    red[t] = v.x + v.y;
    __syncthreads();
    for (int st = 128; st > 0; st >>= 1) {
        if (t < st) red[t] += red[t + st];
        __syncthreads();
    }
    float scale = 1.0f / (red[0] + 1e-4f);
    float2 o; o.x = v.x * scale; o.y = v.y * scale;
    ((float2*)(out + (size_t)r * DD))[t] = o;
}

// ---------------- final L2 normalize + cast to bf16 ----------------
__global__ void l2norm_kernel(const float* __restrict__ in, unsigned short* __restrict__ emb) {
    __shared__ float red[256];
    int r = blockIdx.x, t = threadIdx.x;
    float2 v = ((const float2*)(in + (size_t)r * DD))[t];
    red[t] = v.x * v.x + v.y * v.y;
    __syncthreads();
    for (int st = 128; st > 0; st >>= 1) {
        if (t < st) red[t] += red[t + st];
        __syncthreads();
    }
    float norm = sqrtf(red[0]);
    float scale = 1.0f / fmaxf(norm, 1e-12f);
    ushort2 o;
    o.x = f2bf(v.x * scale);
    o.y = f2bf(v.y * scale);
    ((ushort2*)(emb + (size_t)r * DD))[t] = o;
}

// ---------------- SpMM: agg[dst] += w_e * xn[src], atomic scatter ----------------
// 8 edges per block; 256 threads; float2 (2 features) per thread per edge.
__global__ void spmm_kernel(const int* __restrict__ ei, const float* __restrict__ ew,
                            const float* __restrict__ xn, float* __restrict__ agg) {
    int t = threadIdx.x;
    int e0 = blockIdx.x * 8;
#pragma unroll
    for (int k = 0; k < 8; ++k) {
        int e = e0 + k;
        int dst = ei[e];        // edge_index[0] = dest
        int src = ei[EE + e];   // edge_index[1] = source
        float w = ew[e];
        float2 v = ((const float2*)(xn + (size_t)src * DD))[t];
        float* ar = agg + (size_t)dst * DD + 2 * t;
        unsafeAtomicAdd(ar,     w * v.x);
        unsafeAtomicAdd(ar + 1, w * v.y);
    }
}

// ---------------- fp32 GEMM (NT): C = elu(A @ W^T + b) ----------------
// A [M=NN, K=DD] row-major, W [DD, DD] row-major (rows = output features).
// 64x64 tile, BK=16, 256 threads, 4x4 per thread.
__global__ __launch_bounds__(256) void gemm_bias_elu(const float* __restrict__ A,
                                                     const float* __restrict__ W,
                                                     const float* __restrict__ bias,
                                                     float* __restrict__ C) {
    __shared__ float As[16][68];   // [k][m], +4 pad keeps float4 alignment, breaks conflicts
    __shared__ float Ws[16][68];   // [k][n]
    int t = threadIdx.x;
    int tx = t & 15, ty = t >> 4;
    int row0 = blockIdx.x * 64, col0 = blockIdx.y * 64;
    float acc[4][4] = {};
    int lc = t & 15, lr = t >> 4;
    for (int k0 = 0; k0 < DD; k0 += 16) {
        __syncthreads();
#pragma unroll
        for (int i = 0; i < 4; ++i) {
            int r = lr + 16 * i;
            As[lc][r] = A[(size_t)(row0 + r) * DD + k0 + lc];
            Ws[lc][r] = W[(size_t)(col0 + r) * DD + k0 + lc];
        }
        __syncthreads();
#pragma unroll
        for (int kk = 0; kk < 16; ++kk) {
            float4 a4 = *(const float4*)&As[kk][ty * 4];
            float4 w4 = *(const float4*)&Ws[kk][tx * 4];
            float av[4] = {a4.x, a4.y, a4.z, a4.w};
            float wv[4] = {w4.x, w4.y, w4.z, w4.w};
#pragma unroll
            for (int i = 0; i < 4; ++i)
#pragma unroll
                for (int j = 0; j < 4; ++j)
                    acc[i][j] += av[i] * wv[j];
        }
    }
#pragma unroll
    for (int i = 0; i < 4; ++i) {
        int r = row0 + ty * 4 + i;
#pragma unroll
        for (int j = 0; j < 4; ++j) {
            int c = col0 + tx * 4 + j;
            float v = acc[i][j] + bias[c];
            C[(size_t)r * DD + c] = v > 0.0f ? v : expm1f(v);
        }
    }
}

// ---------------- similarity GEMM: out = relu(emb @ emb^T), bf16 MFMA ----------------
// m97 structure: 128x128 block tile, 4 waves in 2x2, each wave 4x4 of 16x16x32 MFMA,
// BK=32, global_load_lds width 16 (LDS dest = wave-uniform base + lane*16).
__device__ inline void gl_lds16(const void* g, void* l) {
    __builtin_amdgcn_global_load_lds((const __attribute__((address_space(1))) void*)g,
                                     (__attribute__((address_space(3))) void*)l, 16, 0, 0);
}

__global__ __launch_bounds__(256, 2) void simgemm_kernel(const unsigned short* __restrict__ A,
                                                         float* __restrict__ C) {
    __shared__ unsigned short lsA[128 * 32];  // 8 KB
    __shared__ unsigned short lsB[128 * 32];  // 8 KB
    const int K = DD;
    int tid = threadIdx.x;
    int wave = tid >> 6, lane = tid & 63;
    int quad = lane >> 4, l16 = lane & 15;
    int row0 = blockIdx.x * 128, col0 = blockIdx.y * 128;
    int wm = (wave >> 1) * 64, wn = (wave & 1) * 64;

    f32x4 acc[4][4] = {};

    int ofs0 = tid * 16;  // byte offset in tile for staging round 0
    for (int k0 = 0; k0 < K; k0 += 32) {
        __syncthreads();  // previous iteration's LDS reads done before overwrite
#pragma unroll
        for (int rnd = 0; rnd < 2; ++rnd) {
            int ofs = rnd * 4096 + ofs0;       // tile bytes: row-major 128 x 32 bf16
            int r = ofs >> 6;                  // 64 B per row
            int c = (ofs & 63) >> 1;           // element col (multiple of 8)
            const unsigned short* ga = A + (size_t)(row0 + r) * K + (k0 + c);
            const unsigned short* gb = A + (size_t)(col0 + r) * K + (k0 + c);
            char* la = (char*)lsA + rnd * 4096 + wave * 1024;  // wave-uniform base
            char* lb = (char*)lsB + rnd * 4096 + wave * 1024;
            gl_lds16(ga, la);
            gl_lds16(gb, lb);
        }
        __syncthreads();  // compiler emits vmcnt(0) before barrier -> LDS writes landed

        bf16x8 afr[4], bfr[4];
#pragma unroll
        for (int mt = 0; mt < 4; ++mt)
            afr[mt] = *(const bf16x8*)&lsA[(wm + mt * 16 + l16) * 32 + quad * 8];
#pragma unroll
        for (int nt = 0; nt < 4; ++nt)
            bfr[nt] = *(const bf16x8*)&lsB[(wn + nt * 16 + l16) * 32 + quad * 8];
#pragma unroll
        for (int mt = 0; mt < 4; ++mt)
#pragma unroll
            for (int nt = 0; nt < 4; ++nt)
                acc[mt][nt] = __builtin_amdgcn_mfma_f32_16x16x32_bf16(afr[mt], bfr[nt],
                                                                      acc[mt][nt], 0, 0, 0);
    }

    // C/D layout (m89-verified): col = lane&15, row = quad*4 + reg
#pragma unroll
    for (int mt = 0; mt < 4; ++mt)
#pragma unroll
        for (int nt = 0; nt < 4; ++nt)
#pragma unroll
            for (int i = 0; i < 4; ++i) {
                int r = row0 + wm + mt * 16 + quad * 4 + i;
                int c = col0 + wn + nt * 16 + l16;
                C[(size_t)r * NN + c] = fmaxf(acc[mt][nt][i], 0.0f);
            }
}

extern "C" void kernel_launch(void* const* d_in, const int* in_sizes, int n_in,
                              void* d_out, int out_size, void* d_ws, size_t ws_size,
                              hipStream_t stream) {
    const float* x  = (const float*)d_in[0];
    const int*   ei = (const int*)d_in[1];
    const float* ew = (const float*)d_in[2];
    const float* W  = (const float*)d_in[3];
    const float* b  = (const float*)d_in[4];
    float* out = (float*)d_out;

    // workspace: xn [NN*DD] f32 | agg [NN*DD] f32 (emb bf16 aliases agg once dead)
    float* xn  = (float*)d_ws;
    float* agg = xn + (size_t)NN * DD;
    unsigned short* emb = (unsigned short*)agg;

    const float* cur = x;
    for (int layer = 0; layer < 2; ++layer) {
        rownorm_kernel<<<NN, 256, 0, stream>>>(cur, xn);
        hipMemsetAsync(agg, 0, (size_t)NN * DD * sizeof(float), stream);
        spmm_kernel<<<EE / 8, 256, 0, stream>>>(ei, ew, xn, agg);
        gemm_bias_elu<<<dim3(NN / 64, DD / 64), 256, 0, stream>>>(agg, W, b, xn);
        cur = xn;
    }
    l2norm_kernel<<<NN, 256, 0, stream>>>(xn, emb);
    simgemm_kernel<<<dim3(NN / 128, NN / 128), 256, 0, stream>>>(emb, out);
}

// Round 2
// 646.723 us; speedup vs baseline: 3.3476x; 3.3476x over previous
//
#include <hip/hip_runtime.h>

#define NN 8192
#define DD 512
#define EE 262144

typedef __attribute__((ext_vector_type(4))) float f32x4;
typedef __attribute__((ext_vector_type(8))) short bf16x8;

__device__ inline unsigned short f2bf(float f) {
    unsigned u = __float_as_uint(f);
    u += 0x7fffu + ((u >> 16) & 1u);   // round-to-nearest-even
    return (unsigned short)(u >> 16);
}

// ---------------- row-sum normalize: out = in / (rowsum + 1e-4) ----------------
__global__ void rownorm_kernel(const float* __restrict__ in, float* __restrict__ out) {
    __shared__ float red[256];
    int r = blockIdx.x, t = threadIdx.x;
    float2 v = ((const float2*)(in + (size_t)r * DD))[t];
    red[t] = v.x + v.y;
    __syncthreads();
    for (int st = 128; st > 0; st >>= 1) {
        if (t < st) red[t] += red[t + st];
        __syncthreads();
    }
    float scale = 1.0f / (red[0] + 1e-4f);
    float2 o; o.x = v.x * scale; o.y = v.y * scale;
    ((float2*)(out + (size_t)r * DD))[t] = o;
}

// ---------------- final L2 normalize + cast to bf16 ----------------
__global__ void l2norm_kernel(const float* __restrict__ in, unsigned short* __restrict__ emb) {
    __shared__ float red[256];
    int r = blockIdx.x, t = threadIdx.x;
    float2 v = ((const float2*)(in + (size_t)r * DD))[t];
    red[t] = v.x * v.x + v.y * v.y;
    __syncthreads();
    for (int st = 128; st > 0; st >>= 1) {
        if (t < st) red[t] += red[t + st];
        __syncthreads();
    }
    float norm = sqrtf(red[0]);
    float scale = 1.0f / fmaxf(norm, 1e-12f);
    ushort2 o;
    o.x = f2bf(v.x * scale);
    o.y = f2bf(v.y * scale);
    ((ushort2*)(emb + (size_t)r * DD))[t] = o;
}

// ================= CSR build (once per call; edge_index constant across layers) ======
// hist: cnt[dst]++ per edge
__global__ void hist_kernel(const int* __restrict__ ei, int* __restrict__ cnt) {
    int e = blockIdx.x * 256 + threadIdx.x;
    atomicAdd(&cnt[ei[e]], 1);
}

// single-block exclusive scan of cnt[0..NN) -> row_ptr; rewrites cnt[i] = row start
// (cnt buffer then serves as the scatter cursor)
__global__ void scan_kernel(int* __restrict__ cnt, int* __restrict__ row_ptr) {
    __shared__ int part[256];
    int t = threadIdx.x;
    int base = t * 32;
    int local[32];
    int s = 0;
#pragma unroll
    for (int i = 0; i < 32; ++i) { local[i] = s; s += cnt[base + i]; }
    part[t] = s;
    __syncthreads();
    // inclusive Hillis-Steele over 256 partials
    for (int st = 1; st < 256; st <<= 1) {
        int add = (t >= st) ? part[t - st] : 0;
        __syncthreads();
        part[t] += add;
        __syncthreads();
    }
    int offset = part[t] - s;  // exclusive prefix for this chunk
#pragma unroll
    for (int i = 0; i < 32; ++i) {
        row_ptr[base + i] = offset + local[i];
        cnt[base + i] = offset + local[i];
    }
    if (t == 255) row_ptr[NN] = part[255];
}

// scatter edges into CSR order (order within a row is arbitrary — sums commute)
__global__ void scatter_kernel(const int* __restrict__ ei, const float* __restrict__ ew,
                               int* __restrict__ cursor, int* __restrict__ s_src,
                               float* __restrict__ s_w) {
    int e = blockIdx.x * 256 + threadIdx.x;
    int dst = ei[e];
    int pos = atomicAdd(&cursor[dst], 1);
    s_src[pos] = ei[EE + e];
    s_w[pos]   = ew[e];
}

// ---------------- SpMM gather: agg[r] = sum_e w_e * xn[src_e], one block per row ----
__global__ __launch_bounds__(256) void gather_spmm(const int* __restrict__ row_ptr,
                                                   const int* __restrict__ s_src,
                                                   const float* __restrict__ s_w,
                                                   const float* __restrict__ xn,
                                                   float* __restrict__ agg) {
    int r = blockIdx.x, t = threadIdx.x;
    int beg = row_ptr[r], end = row_ptr[r + 1];
    float2 acc; acc.x = 0.0f; acc.y = 0.0f;
    int e = beg;
    for (; e + 2 <= end; e += 2) {
        int s0 = s_src[e], s1 = s_src[e + 1];       // block-uniform -> scalar loads
        float w0 = s_w[e], w1 = s_w[e + 1];
        float2 v0 = ((const float2*)(xn + (size_t)s0 * DD))[t];
        float2 v1 = ((const float2*)(xn + (size_t)s1 * DD))[t];
        acc.x += w0 * v0.x + w1 * v1.x;
        acc.y += w0 * v0.y + w1 * v1.y;
    }
    if (e < end) {
        int s0 = s_src[e];
        float w0 = s_w[e];
        float2 v0 = ((const float2*)(xn + (size_t)s0 * DD))[t];
        acc.x += w0 * v0.x;
        acc.y += w0 * v0.y;
    }
    ((float2*)(agg + (size_t)r * DD))[t] = acc;
}

// ---------------- fp32 GEMM (NT): C = elu(A @ W^T + b) ----------------
__global__ __launch_bounds__(256) void gemm_bias_elu(const float* __restrict__ A,
                                                     const float* __restrict__ W,
                                                     const float* __restrict__ bias,
                                                     float* __restrict__ C) {
    __shared__ float As[16][68];
    __shared__ float Ws[16][68];
    int t = threadIdx.x;
    int tx = t & 15, ty = t >> 4;
    int row0 = blockIdx.x * 64, col0 = blockIdx.y * 64;
    float acc[4][4] = {};
    int lc = t & 15, lr = t >> 4;
    for (int k0 = 0; k0 < DD; k0 += 16) {
        __syncthreads();
#pragma unroll
        for (int i = 0; i < 4; ++i) {
            int r = lr + 16 * i;
            As[lc][r] = A[(size_t)(row0 + r) * DD + k0 + lc];
            Ws[lc][r] = W[(size_t)(col0 + r) * DD + k0 + lc];
        }
        __syncthreads();
#pragma unroll
        for (int kk = 0; kk < 16; ++kk) {
            float4 a4 = *(const float4*)&As[kk][ty * 4];
            float4 w4 = *(const float4*)&Ws[kk][tx * 4];
            float av[4] = {a4.x, a4.y, a4.z, a4.w};
            float wv[4] = {w4.x, w4.y, w4.z, w4.w};
#pragma unroll
            for (int i = 0; i < 4; ++i)
#pragma unroll
                for (int j = 0; j < 4; ++j)
                    acc[i][j] += av[i] * wv[j];
        }
    }
#pragma unroll
    for (int i = 0; i < 4; ++i) {
        int r = row0 + ty * 4 + i;
#pragma unroll
        for (int j = 0; j < 4; ++j) {
            int c = col0 + tx * 4 + j;
            float v = acc[i][j] + bias[c];
            C[(size_t)r * DD + c] = v > 0.0f ? v : expm1f(v);
        }
    }
}

// ---------------- similarity GEMM: out = relu(emb @ emb^T), bf16 MFMA ----------------
__device__ inline void gl_lds16(const void* g, void* l) {
    __builtin_amdgcn_global_load_lds((const __attribute__((address_space(1))) void*)g,
                                     (__attribute__((address_space(3))) void*)l, 16, 0, 0);
}

__global__ __launch_bounds__(256, 2) void simgemm_kernel(const unsigned short* __restrict__ A,
                                                         float* __restrict__ C) {
    __shared__ unsigned short lsA[128 * 32];
    __shared__ unsigned short lsB[128 * 32];
    const int K = DD;
    int tid = threadIdx.x;
    int wave = tid >> 6, lane = tid & 63;
    int quad = lane >> 4, l16 = lane & 15;
    int row0 = blockIdx.x * 128, col0 = blockIdx.y * 128;
    int wm = (wave >> 1) * 64, wn = (wave & 1) * 64;

    f32x4 acc[4][4] = {};

    int ofs0 = tid * 16;
    for (int k0 = 0; k0 < K; k0 += 32) {
        __syncthreads();
#pragma unroll
        for (int rnd = 0; rnd < 2; ++rnd) {
            int ofs = rnd * 4096 + ofs0;
            int r = ofs >> 6;
            int c = (ofs & 63) >> 1;
            const unsigned short* ga = A + (size_t)(row0 + r) * K + (k0 + c);
            const unsigned short* gb = A + (size_t)(col0 + r) * K + (k0 + c);
            char* la = (char*)lsA + rnd * 4096 + wave * 1024;
            char* lb = (char*)lsB + rnd * 4096 + wave * 1024;
            gl_lds16(ga, la);
            gl_lds16(gb, lb);
        }
        __syncthreads();

        bf16x8 afr[4], bfr[4];
#pragma unroll
        for (int mt = 0; mt < 4; ++mt)
            afr[mt] = *(const bf16x8*)&lsA[(wm + mt * 16 + l16) * 32 + quad * 8];
#pragma unroll
        for (int nt = 0; nt < 4; ++nt)
            bfr[nt] = *(const bf16x8*)&lsB[(wn + nt * 16 + l16) * 32 + quad * 8];
#pragma unroll
        for (int mt = 0; mt < 4; ++mt)
#pragma unroll
            for (int nt = 0; nt < 4; ++nt)
                acc[mt][nt] = __builtin_amdgcn_mfma_f32_16x16x32_bf16(afr[mt], bfr[nt],
                                                                      acc[mt][nt], 0, 0, 0);
    }

#pragma unroll
    for (int mt = 0; mt < 4; ++mt)
#pragma unroll
        for (int nt = 0; nt < 4; ++nt)
#pragma unroll
            for (int i = 0; i < 4; ++i) {
                int r = row0 + wm + mt * 16 + quad * 4 + i;
                int c = col0 + wn + nt * 16 + l16;
                C[(size_t)r * NN + c] = fmaxf(acc[mt][nt][i], 0.0f);
            }
}

extern "C" void kernel_launch(void* const* d_in, const int* in_sizes, int n_in,
                              void* d_out, int out_size, void* d_ws, size_t ws_size,
                              hipStream_t stream) {
    const float* x  = (const float*)d_in[0];
    const int*   ei = (const int*)d_in[1];
    const float* ew = (const float*)d_in[2];
    const float* W  = (const float*)d_in[3];
    const float* b  = (const float*)d_in[4];
    float* out = (float*)d_out;

    // workspace layout (floats/ints are 4 B each):
    // xn [NN*DD] | agg [NN*DD] | row_ptr [NN+1] | cur_cnt [NN] | s_src [EE] | s_w [EE]
    float* xn  = (float*)d_ws;
    float* agg = xn + (size_t)NN * DD;
    int* row_ptr = (int*)(agg + (size_t)NN * DD);
    int* cur_cnt = row_ptr + (NN + 1);
    int* s_src   = cur_cnt + NN;
    float* s_w   = (float*)(s_src + EE);
    unsigned short* emb = (unsigned short*)agg;   // agg dead after last gemm

    // ---- build CSR once (same edges both layers) ----
    hipMemsetAsync(cur_cnt, 0, NN * sizeof(int), stream);
    hist_kernel<<<EE / 256, 256, 0, stream>>>(ei, cur_cnt);
    scan_kernel<<<1, 256, 0, stream>>>(cur_cnt, row_ptr);
    scatter_kernel<<<EE / 256, 256, 0, stream>>>(ei, ew, cur_cnt, s_src, s_w);

    const float* cur = x;
    for (int layer = 0; layer < 2; ++layer) {
        rownorm_kernel<<<NN, 256, 0, stream>>>(cur, xn);
        gather_spmm<<<NN, 256, 0, stream>>>(row_ptr, s_src, s_w, xn, agg);
        gemm_bias_elu<<<dim3(NN / 64, DD / 64), 256, 0, stream>>>(agg, W, b, xn);
        cur = xn;
    }
    l2norm_kernel<<<NN, 256, 0, stream>>>(xn, emb);
    simgemm_kernel<<<dim3(NN / 128, NN / 128), 256, 0, stream>>>(emb, out);
}

// Round 3
// 571.846 us; speedup vs baseline: 3.7860x; 1.1309x over previous
//
#include <hip/hip_runtime.h>

#define NN 8192
#define DD 512
#define EE 262144

typedef __attribute__((ext_vector_type(4))) float f32x4;
typedef __attribute__((ext_vector_type(8))) short bf16x8;

__device__ inline unsigned short f2bf(float f) {
    unsigned u = __float_as_uint(f);
    u += 0x7fffu + ((u >> 16) & 1u);   // round-to-nearest-even
    return (unsigned short)(u >> 16);
}
__device__ inline float bf2f(unsigned short h) {
    unsigned u = ((unsigned)h) << 16;
    return __uint_as_float(u);
}

// ---------------- row scale: scale[r] = 1/(rowsum + 1e-4) ----------------
__global__ void rowscale_kernel(const float* __restrict__ in, float* __restrict__ scale) {
    __shared__ float red[256];
    int r = blockIdx.x, t = threadIdx.x;
    float2 v = ((const float2*)(in + (size_t)r * DD))[t];
    red[t] = v.x + v.y;
    __syncthreads();
    for (int st = 128; st > 0; st >>= 1) {
        if (t < st) red[t] += red[t + st];
        __syncthreads();
    }
    if (t == 0) scale[r] = 1.0f / (red[0] + 1e-4f);
}

// ---------------- final L2 normalize + cast to bf16 ----------------
__global__ void l2norm_kernel(const float* __restrict__ in, unsigned short* __restrict__ emb) {
    __shared__ float red[256];
    int r = blockIdx.x, t = threadIdx.x;
    float2 v = ((const float2*)(in + (size_t)r * DD))[t];
    red[t] = v.x * v.x + v.y * v.y;
    __syncthreads();
    for (int st = 128; st > 0; st >>= 1) {
        if (t < st) red[t] += red[t + st];
        __syncthreads();
    }
    float norm = sqrtf(red[0]);
    float scale = 1.0f / fmaxf(norm, 1e-12f);
    ushort2 o;
    o.x = f2bf(v.x * scale);
    o.y = f2bf(v.y * scale);
    ((ushort2*)(emb + (size_t)r * DD))[t] = o;
}

// ================= CSR build (once; edge_index constant across layers) ======
__global__ void hist_kernel(const int* __restrict__ ei, int* __restrict__ cnt) {
    int e = blockIdx.x * 256 + threadIdx.x;
    atomicAdd(&cnt[ei[e]], 1);
}

__global__ void scan_kernel(int* __restrict__ cnt, int* __restrict__ row_ptr) {
    __shared__ int part[256];
    int t = threadIdx.x;
    int base = t * 32;
    int local[32];
    int s = 0;
#pragma unroll
    for (int i = 0; i < 32; ++i) { local[i] = s; s += cnt[base + i]; }
    part[t] = s;
    __syncthreads();
    for (int st = 1; st < 256; st <<= 1) {
        int add = (t >= st) ? part[t - st] : 0;
        __syncthreads();
        part[t] += add;
        __syncthreads();
    }
    int offset = part[t] - s;
#pragma unroll
    for (int i = 0; i < 32; ++i) {
        row_ptr[base + i] = offset + local[i];
        cnt[base + i] = offset + local[i];
    }
    if (t == 255) row_ptr[NN] = part[255];
}

__global__ void scatter_kernel(const int* __restrict__ ei, const float* __restrict__ ew,
                               int* __restrict__ cursor, int* __restrict__ s_src,
                               float* __restrict__ s_w) {
    int e = blockIdx.x * 256 + threadIdx.x;
    int dst = ei[e];
    int pos = atomicAdd(&cursor[dst], 1);
    s_src[pos] = ei[EE + e];
    s_w[pos]   = ew[e];
}

// ---------------- split W into bf16 hi/lo (once; W shared by both layers) ----------------
__global__ void splitW_kernel(const float* __restrict__ W, unsigned short* __restrict__ Whi,
                              unsigned short* __restrict__ Wlo) {
    int i = blockIdx.x * 256 + threadIdx.x;   // float2 index
    float2 w = ((const float2*)W)[i];
    ushort2 h, l;
    h.x = f2bf(w.x); l.x = f2bf(w.x - bf2f(h.x));
    h.y = f2bf(w.y); l.y = f2bf(w.y - bf2f(h.y));
    ((ushort2*)Whi)[i] = h;
    ((ushort2*)Wlo)[i] = l;
}

// ---------------- SpMM gather with fused rownorm; emits bf16 hi/lo ----------------
// agg[r] = sum_e (w_e * scale[src_e]) * x[src_e];  one block per dest row.
__global__ __launch_bounds__(256) void gather_spmm_bf16(const int* __restrict__ row_ptr,
                                                        const int* __restrict__ s_src,
                                                        const float* __restrict__ s_w,
                                                        const float* __restrict__ scale,
                                                        const float* __restrict__ x,
                                                        unsigned short* __restrict__ Ahi,
                                                        unsigned short* __restrict__ Alo) {
    int r = blockIdx.x, t = threadIdx.x;
    int beg = row_ptr[r], end = row_ptr[r + 1];
    float ax = 0.0f, ay = 0.0f;
    int e = beg;
    for (; e + 2 <= end; e += 2) {
        int s0 = s_src[e], s1 = s_src[e + 1];           // block-uniform -> scalar loads
        float w0 = s_w[e] * scale[s0];
        float w1 = s_w[e + 1] * scale[s1];
        float2 v0 = ((const float2*)(x + (size_t)s0 * DD))[t];
        float2 v1 = ((const float2*)(x + (size_t)s1 * DD))[t];
        ax += w0 * v0.x + w1 * v1.x;
        ay += w0 * v0.y + w1 * v1.y;
    }
    if (e < end) {
        int s0 = s_src[e];
        float w0 = s_w[e] * scale[s0];
        float2 v0 = ((const float2*)(x + (size_t)s0 * DD))[t];
        ax += w0 * v0.x;
        ay += w0 * v0.y;
    }
    ushort2 h, l;
    h.x = f2bf(ax); l.x = f2bf(ax - bf2f(h.x));
    h.y = f2bf(ay); l.y = f2bf(ay - bf2f(h.y));
    ((ushort2*)(Ahi + (size_t)r * DD))[t] = h;
    ((ushort2*)(Alo + (size_t)r * DD))[t] = l;
}

// ---------------- async global->LDS helper ----------------
__device__ inline void gl_lds16(const void* g, void* l) {
    __builtin_amdgcn_global_load_lds((const __attribute__((address_space(1))) void*)g,
                                     (__attribute__((address_space(3))) void*)l, 16, 0, 0);
}

// ---------------- layer GEMM: C = elu(A @ W^T + b), bf16-split MFMA ----------------
// A = Ahi+Alo [M=NN][K=DD], W = Whi+Wlo [N=DD][K=DD] (both row-major NT),
// acc += AhiWhi + AhiWlo + AloWhi  (AloWlo term ~2^-18 relative, dropped).
__global__ __launch_bounds__(256, 2) void gemm_split_mfma(const unsigned short* __restrict__ Ahi,
                                                          const unsigned short* __restrict__ Alo,
                                                          const unsigned short* __restrict__ Whi,
                                                          const unsigned short* __restrict__ Wlo,
                                                          const float* __restrict__ bias,
                                                          float* __restrict__ C) {
    __shared__ unsigned short lsAh[128 * 32], lsAl[128 * 32];
    __shared__ unsigned short lsBh[128 * 32], lsBl[128 * 32];
    const int K = DD;
    int tid = threadIdx.x;
    int wave = tid >> 6, lane = tid & 63;
    int quad = lane >> 4, l16 = lane & 15;
    int row0 = blockIdx.x * 128, col0 = blockIdx.y * 128;
    int wm = (wave >> 1) * 64, wn = (wave & 1) * 64;

    f32x4 acc[4][4] = {};

    int ofs0 = tid * 16;
    for (int k0 = 0; k0 < K; k0 += 32) {
        __syncthreads();
#pragma unroll
        for (int rnd = 0; rnd < 2; ++rnd) {
            int ofs = rnd * 4096 + ofs0;
            int r = ofs >> 6;            // 64 B per 32-elem bf16 tile row
            int c = (ofs & 63) >> 1;
            size_t ga = (size_t)(row0 + r) * K + (k0 + c);
            size_t gb = (size_t)(col0 + r) * K + (k0 + c);
            int lofs = rnd * 4096 + wave * 1024;   // wave-uniform LDS base
            gl_lds16(Ahi + ga, (char*)lsAh + lofs);
            gl_lds16(Alo + ga, (char*)lsAl + lofs);
            gl_lds16(Whi + gb, (char*)lsBh + lofs);
            gl_lds16(Wlo + gb, (char*)lsBl + lofs);
        }
        __syncthreads();

        bf16x8 ah[4], al[4], bh[4], bl[4];
#pragma unroll
        for (int mt = 0; mt < 4; ++mt) {
            int o = (wm + mt * 16 + l16) * 32 + quad * 8;
            ah[mt] = *(const bf16x8*)&lsAh[o];
            al[mt] = *(const bf16x8*)&lsAl[o];
        }
#pragma unroll
        for (int nt = 0; nt < 4; ++nt) {
            int o = (wn + nt * 16 + l16) * 32 + quad * 8;
            bh[nt] = *(const bf16x8*)&lsBh[o];
            bl[nt] = *(const bf16x8*)&lsBl[o];
        }
#pragma unroll
        for (int mt = 0; mt < 4; ++mt)
#pragma unroll
            for (int nt = 0; nt < 4; ++nt) {
                acc[mt][nt] = __builtin_amdgcn_mfma_f32_16x16x32_bf16(ah[mt], bh[nt], acc[mt][nt], 0, 0, 0);
                acc[mt][nt] = __builtin_amdgcn_mfma_f32_16x16x32_bf16(ah[mt], bl[nt], acc[mt][nt], 0, 0, 0);
                acc[mt][nt] = __builtin_amdgcn_mfma_f32_16x16x32_bf16(al[mt], bh[nt], acc[mt][nt], 0, 0, 0);
            }
    }

    // C/D layout: col = lane&15, row = quad*4 + reg
#pragma unroll
    for (int mt = 0; mt < 4; ++mt)
#pragma unroll
        for (int nt = 0; nt < 4; ++nt)
#pragma unroll
            for (int i = 0; i < 4; ++i) {
                int r = row0 + wm + mt * 16 + quad * 4 + i;
                int c = col0 + wn + nt * 16 + l16;
                float v = acc[mt][nt][i] + bias[c];
                C[(size_t)r * DD + c] = v > 0.0f ? v : expm1f(v);
            }
}

// ---------------- similarity GEMM: out = relu(emb @ emb^T), bf16 MFMA ----------------
__global__ __launch_bounds__(256, 2) void simgemm_kernel(const unsigned short* __restrict__ A,
                                                         float* __restrict__ C) {
    __shared__ unsigned short lsA[128 * 32];
    __shared__ unsigned short lsB[128 * 32];
    const int K = DD;
    int tid = threadIdx.x;
    int wave = tid >> 6, lane = tid & 63;
    int quad = lane >> 4, l16 = lane & 15;
    int row0 = blockIdx.x * 128, col0 = blockIdx.y * 128;
    int wm = (wave >> 1) * 64, wn = (wave & 1) * 64;

    f32x4 acc[4][4] = {};

    int ofs0 = tid * 16;
    for (int k0 = 0; k0 < K; k0 += 32) {
        __syncthreads();
#pragma unroll
        for (int rnd = 0; rnd < 2; ++rnd) {
            int ofs = rnd * 4096 + ofs0;
            int r = ofs >> 6;
            int c = (ofs & 63) >> 1;
            const unsigned short* ga = A + (size_t)(row0 + r) * K + (k0 + c);
            const unsigned short* gb = A + (size_t)(col0 + r) * K + (k0 + c);
            char* la = (char*)lsA + rnd * 4096 + wave * 1024;
            char* lb = (char*)lsB + rnd * 4096 + wave * 1024;
            gl_lds16(ga, la);
            gl_lds16(gb, lb);
        }
        __syncthreads();

        bf16x8 afr[4], bfr[4];
#pragma unroll
        for (int mt = 0; mt < 4; ++mt)
            afr[mt] = *(const bf16x8*)&lsA[(wm + mt * 16 + l16) * 32 + quad * 8];
#pragma unroll
        for (int nt = 0; nt < 4; ++nt)
            bfr[nt] = *(const bf16x8*)&lsB[(wn + nt * 16 + l16) * 32 + quad * 8];
#pragma unroll
        for (int mt = 0; mt < 4; ++mt)
#pragma unroll
            for (int nt = 0; nt < 4; ++nt)
                acc[mt][nt] = __builtin_amdgcn_mfma_f32_16x16x32_bf16(afr[mt], bfr[nt],
                                                                      acc[mt][nt], 0, 0, 0);
    }

#pragma unroll
    for (int mt = 0; mt < 4; ++mt)
#pragma unroll
        for (int nt = 0; nt < 4; ++nt)
#pragma unroll
            for (int i = 0; i < 4; ++i) {
                int r = row0 + wm + mt * 16 + quad * 4 + i;
                int c = col0 + wn + nt * 16 + l16;
                C[(size_t)r * NN + c] = fmaxf(acc[mt][nt][i], 0.0f);
            }
}

extern "C" void kernel_launch(void* const* d_in, const int* in_sizes, int n_in,
                              void* d_out, int out_size, void* d_ws, size_t ws_size,
                              hipStream_t stream) {
    const float* x  = (const float*)d_in[0];
    const int*   ei = (const int*)d_in[1];
    const float* ew = (const float*)d_in[2];
    const float* W  = (const float*)d_in[3];
    const float* b  = (const float*)d_in[4];
    float* out = (float*)d_out;

    // workspace layout:
    // y [NN*DD] f32 | Ahi [NN*DD] bf16 | Alo [NN*DD] bf16 | Whi,Wlo [DD*DD] bf16
    // | scale [NN] f32 | row_ptr [NN+1] | cur_cnt [NN] | s_src [EE] | s_w [EE]
    float* y = (float*)d_ws;
    unsigned short* Ahi = (unsigned short*)(y + (size_t)NN * DD);
    unsigned short* Alo = Ahi + (size_t)NN * DD;
    unsigned short* Whi = Alo + (size_t)NN * DD;
    unsigned short* Wlo = Whi + (size_t)DD * DD;
    float* scale  = (float*)(Wlo + (size_t)DD * DD);
    int* row_ptr  = (int*)(scale + NN);
    int* cur_cnt  = row_ptr + (NN + 1);
    int* s_src    = cur_cnt + NN;
    float* s_w    = (float*)(s_src + EE);
    unsigned short* emb = Ahi;   // Ahi dead after layer-2 gemm

    // ---- CSR build (edges identical across layers) ----
    hipMemsetAsync(cur_cnt, 0, NN * sizeof(int), stream);
    hist_kernel<<<EE / 256, 256, 0, stream>>>(ei, cur_cnt);
    scan_kernel<<<1, 256, 0, stream>>>(cur_cnt, row_ptr);
    scatter_kernel<<<EE / 256, 256, 0, stream>>>(ei, ew, cur_cnt, s_src, s_w);
    splitW_kernel<<<(DD * DD / 2) / 256, 256, 0, stream>>>(W, Whi, Wlo);

    const float* cur = x;
    for (int layer = 0; layer < 2; ++layer) {
        rowscale_kernel<<<NN, 256, 0, stream>>>(cur, scale);
        gather_spmm_bf16<<<NN, 256, 0, stream>>>(row_ptr, s_src, s_w, scale, cur, Ahi, Alo);
        gemm_split_mfma<<<dim3(NN / 128, DD / 128), 256, 0, stream>>>(Ahi, Alo, Whi, Wlo, b, y);
        cur = y;
    }
    l2norm_kernel<<<NN, 256, 0, stream>>>(y, emb);
    simgemm_kernel<<<dim3(NN / 128, NN / 128), 256, 0, stream>>>(emb, out);
}